// Round 5
// baseline (534.776 us; speedup 1.0000x reference)
//
#include <hip/hip_runtime.h>

// QuantizedLinear: out[M,N] = (x[M,K] @ W^T) * scale + bias, W[N,K] = q - zp
// M = 8192, N = 4096, K = 4096.
// GEMM: 256x256 tile, BK=64, 8 waves (2 row x 4 col), 32x32x16 bf16 MFMA.
// 2 phases per K-tile (phase = k-half), symmetric schedule: per phase
// 12 ds_read_b128 + 4 global_load_lds + 16 MFMA + vmcnt(8) + barrier.
// LDS double-buffer by k-half slots [256 rows][32 k] (16KB each, 128KB total),
// involution XOR swizzle (2-way = free), pre-swizzled global source,
// setprio around MFMA, XCD block swizzle.

typedef __bf16 bf16x8 __attribute__((ext_vector_type(8)));
typedef float  f32x16 __attribute__((ext_vector_type(16)));

// ---------------- conversion kernels (unchanged) ----------------

__global__ __launch_bounds__(256) void cvt_x_bf16(
    const float4* __restrict__ x, uint4* __restrict__ o, int n8) {
  int i = blockIdx.x * 256 + threadIdx.x;
  if (i >= n8) return;
  float4 a = x[2 * i];
  float4 b = x[2 * i + 1];
  union { __bf16 h[8]; uint4 u; } r;
  r.h[0] = (__bf16)a.x; r.h[1] = (__bf16)a.y;
  r.h[2] = (__bf16)a.z; r.h[3] = (__bf16)a.w;
  r.h[4] = (__bf16)b.x; r.h[5] = (__bf16)b.y;
  r.h[6] = (__bf16)b.z; r.h[7] = (__bf16)b.w;
  o[i] = r.u;
}

__global__ __launch_bounds__(256) void cvt_w_bf16(
    const int4* __restrict__ q, const int* __restrict__ zp,
    uint4* __restrict__ o, int n8) {
  int i = blockIdx.x * 256 + threadIdx.x;
  if (i >= n8) return;
  int z = zp[0];
  int4 a = q[2 * i];
  int4 b = q[2 * i + 1];
  union { __bf16 h[8]; uint4 u; } r;
  r.h[0] = (__bf16)(float)(a.x - z); r.h[1] = (__bf16)(float)(a.y - z);
  r.h[2] = (__bf16)(float)(a.z - z); r.h[3] = (__bf16)(float)(a.w - z);
  r.h[4] = (__bf16)(float)(b.x - z); r.h[5] = (__bf16)(float)(b.y - z);
  r.h[6] = (__bf16)(float)(b.z - z); r.h[7] = (__bf16)(float)(b.w - z);
  o[i] = r.u;
}

// ---------------- 256^2 GEMM, 32x32x16, k-half slots ----------------
// Slot (d, kh): [256 rows][32 k-cols] bf16 = 16KB. A at 0..64KB, B at 64..128KB.
// Subtile layout: 16 rows x 32 cols (1KB), inner byte(r,c) =
//   (r&15)*64 + (c*2 ^ swz(r)), swz(r) = ((r>>1)&3)<<4. Involution; staging
// writes linear with the inverse swizzle folded into the global source col.
//
// Per tile t (d = t&1, e = d^1):
//  ph1 (kh0): read af/bf k-cols 0..31 | stage A,B(t+1, kh1) | 16 MFMA
//             | vmcnt(8) [(t,kh1) ready] | barrier
//  ph2 (kh1): read af/bf k-cols 32..63 | stage A,B(t+2, kh0) | 16 MFMA
//             | vmcnt(8) [(t+1,kh0) ready] | barrier
// Stage safety: (e,kh1) last read ph2(t-1), barrier intervenes; (d,kh0) last
// read ph1(t), barrier intervenes. Ledger: entering ph1(t) outstanding =
// [(t,k1):4, (t+1,k0):4]; +4 -> vmcnt(8) completes (t,k1); ph2 +4 ->
// vmcnt(8) completes (t+1,k0).

#define SLOT32_A(d, kh) ((((d) * 2 + (kh)) << 14))
#define SLOT32_B(d, kh) ((1 << 16) + (((d) * 2 + (kh)) << 14))

#define WAITVM_(n) asm volatile("s_waitcnt vmcnt(" #n ")")
#define WAITVM(n) WAITVM_(n)

// Stage one k-half (256 rows x 32 cols = 16KB): 2 gload_lds per wave.
// gbase row = by*256 + wave*32 + (lane>>2), col byte = colLane (pre-swizzled).
#define STAGE32(gbase, ldsOff, kh, s)                                         \
  do {                                                                        \
    const char* g_ = (gbase) + (size_t)(kh) * 64 + (size_t)(s) * 128;         \
    __builtin_amdgcn_global_load_lds(                                         \
        (const __attribute__((address_space(1))) void*)(g_),                  \
        (__attribute__((address_space(3))) void*)(smem + (ldsOff) + wave * 2048), \
        16, 0, 0);                                                            \
    __builtin_amdgcn_global_load_lds(                                         \
        (const __attribute__((address_space(1))) void*)(g_ + 16 * K2),        \
        (__attribute__((address_space(3))) void*)(smem + (ldsOff) + wave * 2048 + 1024), \
        16, 0, 0);                                                            \
  } while (0)

// A frag: row = wr*128 + mrf*32 + (l&31), k = ks2*16 + (l>>5)*8 + e.
#define LOAD_A32(d, kh)                                                       \
  do {                                                                        \
    _Pragma("unroll") for (int mrf = 0; mrf < 4; ++mrf)                       \
    _Pragma("unroll") for (int ks2 = 0; ks2 < 2; ++ks2)                       \
        af[mrf][ks2] = *(const bf16x8*)(smem + SLOT32_A(d, kh) + aSub +       \
            mrf * 2048 + ((ks2 << 5) ^ kLo));                                 \
  } while (0)

// B frag: col = wc*64 + nf*32 + (l&31), k = ks2*16 + (l>>5)*8 + e.
#define LOAD_B32(d, kh)                                                       \
  do {                                                                        \
    _Pragma("unroll") for (int nf = 0; nf < 2; ++nf)                          \
    _Pragma("unroll") for (int ks2 = 0; ks2 < 2; ++ks2)                       \
        bf[nf][ks2] = *(const bf16x8*)(smem + SLOT32_B(d, kh) + bSub +        \
            nf * 2048 + ((ks2 << 5) ^ kLo));                                  \
  } while (0)

// ks2 outermost: 8 independent MFMAs before any same-accumulator reuse.
#define MFMA32()                                                              \
  do {                                                                        \
    __builtin_amdgcn_s_setprio(1);                                            \
    _Pragma("unroll") for (int ks2 = 0; ks2 < 2; ++ks2)                       \
    _Pragma("unroll") for (int mrf = 0; mrf < 4; ++mrf)                       \
    _Pragma("unroll") for (int nf = 0; nf < 2; ++nf)                          \
        acc[mrf][nf] = __builtin_amdgcn_mfma_f32_32x32x16_bf16(               \
            af[mrf][ks2], bf[nf][ks2], acc[mrf][nf], 0, 0, 0);                \
    __builtin_amdgcn_s_setprio(0);                                            \
  } while (0)

// S1: stage (t+1,kh1) in ph1; S2: stage (t+2,kh0) in ph2.
#define TILE32(t, d, e, S1, S2)                                               \
  do {                                                                        \
    /* ph1: kh0 */                                                            \
    LOAD_A32(d, 0);                                                           \
    LOAD_B32(d, 0);                                                           \
    if (S1) { STAGE32(Abase, SLOT32_A(e, 1), 1, (t) + 1);                     \
              STAGE32(Bbase, SLOT32_B(e, 1), 1, (t) + 1); }                   \
    MFMA32();                                                                 \
    if (S1) { WAITVM(8); } else { WAITVM(0); }                                \
    __builtin_amdgcn_s_barrier();                                             \
    /* ph2: kh1 */                                                            \
    LOAD_A32(d, 1);                                                           \
    LOAD_B32(d, 1);                                                           \
    if (S2) { STAGE32(Abase, SLOT32_A(d, 0), 0, (t) + 2);                     \
              STAGE32(Bbase, SLOT32_B(d, 0), 0, (t) + 2); }                   \
    MFMA32();                                                                 \
    if (S2) { WAITVM(8); } else if (S1) { WAITVM(4); }                        \
    __builtin_amdgcn_s_barrier();                                             \
  } while (0)

__global__ __launch_bounds__(512, 2) void gemm256(
    const __bf16* __restrict__ A, const __bf16* __restrict__ Bw,
    const float* __restrict__ scale, const float* __restrict__ bias,
    float* __restrict__ C) {
  extern __shared__ char smem[];

  constexpr int N = 4096, K = 4096;
  constexpr size_t K2 = (size_t)K * 2;  // row stride in bytes

  const int tid  = threadIdx.x;
  const int wave = tid >> 6;
  const int lane = tid & 63;
  const int wr   = wave >> 2;   // 0..1: rows wr*128..+127
  const int wc   = wave & 3;    // 0..3: cols wc*64..+63

  // T1: XCD swizzle, nwg = 512 (divisible by 8).
  const int nwg = gridDim.x;
  const int cpx = nwg >> 3;
  const int swzid = ((int)blockIdx.x & 7) * cpx + ((int)blockIdx.x >> 3);
  const int nbx = N >> 8;          // 16
  const int bx = swzid % nbx;
  const int by = swzid / nbx;

  // staging per-lane source: row = wave*32 + i*16 + (lane>>2),
  // col byte = ((lane&3)<<4) ^ (((lane>>3)&3)<<4)  (inverse swizzle)
  const int rowLane = wave * 32 + (lane >> 2);
  const int colLane = ((lane & 3) << 4) ^ (((lane >> 3) & 3) << 4);
  const char* Abase = (const char*)A  + (size_t)(by * 256 + rowLane) * K2 + colLane;
  const char* Bbase = (const char*)Bw + (size_t)(bx * 256 + rowLane) * K2 + colLane;

  // ds_read per-lane constants:
  // subtile index r>>4 = wr*8 + mrf*2 + ((l&31)>>4); inner row = l&15;
  // k-byte = (ks2<<5) ^ ((l>>5)<<4) ^ swz, swz = ((l>>1)&3)<<4.
  const int aSub = (wr * 8 + ((lane >> 4) & 1)) * 1024 + ((lane & 15) << 6);
  const int bSub = (wc * 4 + ((lane >> 4) & 1)) * 1024 + ((lane & 15) << 6);
  const int kLo  = (((lane >> 5) & 1) << 4) ^ (((lane >> 1) & 3) << 4);

  f32x16 acc[4][2] = {};
  bf16x8 af[4][2], bf[2][2];

  // prologue ledger: [0k0 A,B][0k1 A,B][1k0 A,B] = 12 in flight.
  STAGE32(Abase, SLOT32_A(0, 0), 0, 0);
  STAGE32(Bbase, SLOT32_B(0, 0), 0, 0);
  STAGE32(Abase, SLOT32_A(0, 1), 1, 0);
  STAGE32(Bbase, SLOT32_B(0, 1), 1, 0);
  STAGE32(Abase, SLOT32_A(1, 0), 0, 1);
  STAGE32(Bbase, SLOT32_B(1, 0), 0, 1);
  WAITVM(8);                       // oldest 4 = (0,kh0) complete
  __builtin_amdgcn_s_barrier();

  for (int tt = 0; tt < 62; tt += 2) {
    TILE32(tt,     0, 1, 1, 1);
    TILE32(tt + 1, 1, 0, 1, 1);
  }
  TILE32(62, 0, 1, 1, 0);   // ph1 stages (63,k1) vmcnt(8); ph2 vmcnt(4)
  TILE32(63, 1, 0, 0, 0);   // ph1 vmcnt(0); ph2 no wait

  // epilogue: 32x32 C/D layout: col = lane&31,
  // row = (reg&3) + 8*(reg>>2) + 4*(lane>>5)  (m74/m101-verified)
  const float s = scale[0];
#pragma unroll
  for (int mrf = 0; mrf < 4; ++mrf) {
    const int row0 = by * 256 + wr * 128 + mrf * 32 + ((lane >> 5) << 2);
#pragma unroll
    for (int nf = 0; nf < 2; ++nf) {
      const int col = bx * 256 + wc * 64 + nf * 32 + (lane & 31);
      const float bv = bias[col];
#pragma unroll
      for (int g = 0; g < 4; ++g) {
        float* cp = C + (size_t)(row0 + g * 8) * N + col;
#pragma unroll
        for (int rr = 0; rr < 4; ++rr)
          cp[(size_t)rr * N] = s * acc[mrf][nf][g * 4 + rr] + bv;
      }
    }
  }
}

// ---------------- launch ----------------

extern "C" void kernel_launch(void* const* d_in, const int* in_sizes, int n_in,
                              void* d_out, int out_size, void* d_ws, size_t ws_size,
                              hipStream_t stream) {
  const int M = 8192, N = 4096, K = 4096;

  const float* x    = (const float*)d_in[0];
  const int*   qw   = (const int*)d_in[1];
  const int*   zp   = (const int*)d_in[2];
  const float* sc   = (const float*)d_in[3];
  const float* bias = (const float*)d_in[4];
  float* out = (float*)d_out;

  __bf16* x_bf = (__bf16*)d_ws;
  __bf16* w_bf = (__bf16*)((char*)d_ws + (size_t)M * K * sizeof(__bf16));

  {
    int n8 = (M * K) / 8;
    cvt_x_bf16<<<n8 / 256, 256, 0, stream>>>((const float4*)x, (uint4*)x_bf, n8);
  }
  {
    int n8 = (N * K) / 8;
    cvt_w_bf16<<<n8 / 256, 256, 0, stream>>>((const int4*)qw, zp, (uint4*)w_bf, n8);
  }

  static bool attr_set = false;
  if (!attr_set) {
    hipFuncSetAttribute((const void*)gemm256,
                        hipFuncAttributeMaxDynamicSharedMemorySize, 131072);
    attr_set = true;
  }
  gemm256<<<dim3(512), dim3(512), 131072, stream>>>(x_bf, w_bf, sc, bias, out);
}